// Round 5
// baseline (1391.633 us; speedup 1.0000x reference)
//
#include <hip/hip_runtime.h>

#define NODES   64
#define FRAMES  4096
#define INCH    9
#define H1DIM   256
#define H2DIM   512
#define NEDGE   256

#define CHUNK   64
#define ELLW    16    // ELL width; rows with nnz>16 overflow to tail list (P ~ 1e-6)
#define TAILMAX 64

// ---------------------------------------------------------------------------
// prep: dense normalized A (row=dst, self-loops) -> ELL[64][16] of (val,col)
// packed as float2, + overflow tail list. Zero global accumulator.
// Handles int32 or int64 edge_index.
// ---------------------------------------------------------------------------
__global__ void prep_kernel(const int* __restrict__ ei,
                            float* __restrict__ acc,
                            float2* __restrict__ ellG,      // [64][16]
                            int* __restrict__ tailCntG,
                            int* __restrict__ tailRowG,
                            int* __restrict__ tailColG,
                            float* __restrict__ tailValG)
{
    __shared__ float sA[NODES * NODES];
    __shared__ float dis[NODES];
    __shared__ int   deg[NODES];
    __shared__ int   sTail;
    __shared__ int   flag;
    const int t = threadIdx.x;  // 256 threads
    if (t == 0) { flag = 0; sTail = 0; }
    for (int i = t; i < NODES * NODES; i += 256) sA[i] = 0.f;
    if (t < NODES) deg[t] = 1;  // self-loop
    __syncthreads();
    // int64 little-endian => odd dwords are high words of values <64 => all 0.
    if (ei[2 * t + 1] != 0) atomicOr(&flag, 1);
    __syncthreads();
    const bool is64 = (flag == 0);
    int s = 0, d = 0;
    if (t < NEDGE) {
        if (is64) { s = ei[2 * t];   d = ei[512 + 2 * t]; }
        else      { s = ei[t];       d = ei[NEDGE + t];   }
        atomicAdd(&deg[d], 1);
    }
    __syncthreads();
    if (t < NODES) dis[t] = rsqrtf((float)deg[t]);
    __syncthreads();
    if (t < NEDGE) atomicAdd(&sA[d * NODES + s], dis[s] * dis[d]);  // row = dst
    __syncthreads();
    if (t < NODES) sA[t * NODES + t] += dis[t] * dis[t];
    __syncthreads();
    if (t < NODES) {
        int j = 0;
        for (int m = 0; m < NODES; ++m) {
            float v = sA[t * NODES + m];
            if (v != 0.f) {
                if (j < ELLW) {
                    ellG[t * ELLW + j] = make_float2(v, __int_as_float(m));
                } else {
                    int idx = atomicAdd(&sTail, 1);
                    if (idx < TAILMAX) {
                        tailRowG[idx] = t; tailColG[idx] = m; tailValG[idx] = v;
                    }
                }
                ++j;
            }
        }
        for (; j < ELLW; ++j)
            ellG[t * ELLW + j] = make_float2(0.f, __int_as_float(0));
    }
    __syncthreads();
    if (t == 0) *tailCntG = (sTail < TAILMAX) ? sTail : TAILMAX;
    for (int i = t; i < H2DIM; i += 256) acc[i] = 0.f;
}

// ---------------------------------------------------------------------------
// One block per frame. K-chunked (4 x 64) fused GCN.
//  - Aggregation output stays in REGISTERS (agg[8], lane = chunk-k index);
//    GEMM broadcasts it via v_readlane (SGPR src) -> zero A-side LDS traffic.
//  - W2 staged through LDS in 8-k double-buffered slices (T14 reg-staging);
//    reads are per-lane-distinct coalesced ds_read_b128 (conflict-free).
//  - Per lane: 8 rows x 8 cols (two float4 col-quads at j=4ln and 256+4ln).
// LDS ~66.3 KB -> 2 blocks/CU; regs ~110 < 128 cap from launch_bounds(512,2).
// ---------------------------------------------------------------------------
__global__ __launch_bounds__(512, 2)
void frame_kernel(const float* __restrict__ x,
                  const float2* __restrict__ ellG,
                  const int* __restrict__ tailCntG,
                  const int* __restrict__ tailRowG,
                  const int* __restrict__ tailColG,
                  const float* __restrict__ tailValG,
                  const float* __restrict__ W1,
                  const float* __restrict__ b1,
                  const float* __restrict__ W2,
                  const float* __restrict__ b2,
                  float* __restrict__ acc)
{
    __shared__ __align__(16) float2 sEll[NODES][ELLW];     //  8192 B
    __shared__ float sX [NODES][12];                       //  3072 B
    __shared__ float sAX[NODES][12];                       //  3072 B
    __shared__ __align__(16) float sH1c[NODES][CHUNK];     // 16384 B
    __shared__ __align__(16) float sW2[2][8 * H2DIM];      // 32768 B
    __shared__ float sPart[H2DIM];                         //  2048 B
    __shared__ int   sTR[TAILMAX];
    __shared__ int   sTC[TAILMAX];
    __shared__ float sTV[TAILMAX];
    __shared__ int   sTCnt;                                // => ~66.3 KB

    const int t  = threadIdx.x;
    const int f  = blockIdx.x;
    const int wv = t >> 6;         // wave 0..7 -> rows 8wv..8wv+7
    const int ln = t & 63;         // lane: chunk-k (agg) / col-quad base (GEMM)
    const int n0 = wv * 8;

    // ---- stage ELL, tail, X ----
    for (int i = t; i < NODES * ELLW; i += 512)
        sEll[i >> 4][i & (ELLW - 1)] = ellG[i];
    if (t == 0) sTCnt = *tailCntG;
    if (t < TAILMAX) { sTR[t] = tailRowG[t]; sTC[t] = tailColG[t]; sTV[t] = tailValG[t]; }
    sPart[t] = 0.f;
    for (int i = t; i < NODES * INCH; i += 512) {
        int n = i / INCH, c = i - n * INCH;
        sX[n][c] = x[(n * FRAMES + f) * INCH + c];
    }
    __syncthreads();

    // ---- AX = A*X via ELL ----
    for (int i = t; i < NODES * INCH; i += 512) {
        int n = i / INCH, c = i - n * INCH;
        float v = 0.f;
        #pragma unroll
        for (int j = 0; j < ELLW; ++j) {
            float2 e = sEll[n][j];
            v = fmaf(e.x, sX[__float_as_int(e.y)][c], v);
        }
        sAX[n][c] = v;
    }
    if (sTCnt > 0) {
        __syncthreads();
        if (t < sTCnt * INCH) {
            int e = t / INCH, c = t - e * INCH;
            atomicAdd(&sAX[sTR[e]][c], sTV[e] * sX[sTC[e]][c]);
        }
    }
    __syncthreads();

    float a2[8][8];
    #pragma unroll
    for (int r = 0; r < 8; ++r)
        #pragma unroll
        for (int cc = 0; cc < 8; ++cc) a2[r][cc] = 0.f;

    #pragma unroll 1
    for (int ch = 0; ch < 4; ++ch) {
        const int jb = ch * CHUNK;
        const float* w2base = W2 + (size_t)jb * H2DIM;   // 64 rows x 512 cols

        // ---- issue slice-0 global loads early (hide under layer1) ----
        float4 g0 = *(const float4*)(w2base + 4 * t);
        float4 g1 = *(const float4*)(w2base + 2048 + 4 * t);

        // ---- layer1 chunk: H1c[n][ln] = relu(sum_c AX[n][c]*W1[c][jb+ln]+b1) ----
        {
            float h[8];
            const float bb = b1[jb + ln];
            #pragma unroll
            for (int r = 0; r < 8; ++r) h[r] = bb;
            #pragma unroll
            for (int c = 0; c < INCH; ++c) {
                const float w = W1[c * H1DIM + jb + ln];
                #pragma unroll
                for (int r = 0; r < 8; ++r)
                    h[r] = fmaf(sAX[n0 + r][c], w, h[r]);
            }
            #pragma unroll
            for (int r = 0; r < 8; ++r)
                sH1c[n0 + r][ln] = fmaxf(h[r], 0.f);
        }
        // ---- write slice 0 into buf 0 ----
        *(float4*)&sW2[0][4 * t]        = g0;
        *(float4*)&sW2[0][2048 + 4 * t] = g1;
        __syncthreads();   // sH1c and sW2[0] ready

        // ---- aggregation into registers: agg[r] = (A*H1c)[n0+r][ln] ----
        float agg[8];
        #pragma unroll
        for (int r = 0; r < 8; ++r) {
            float v = 0.f;
            #pragma unroll
            for (int j = 0; j < ELLW; ++j) {
                float2 e = sEll[n0 + r][j];                       // b64 broadcast
                v = fmaf(e.x, sH1c[__float_as_int(e.y)][ln], v);  // lane-stride-1
            }
            agg[r] = v;
        }
        if (sTCnt > 0) {   // virtually never taken (nnz>16 rows)
            #pragma unroll 1
            for (int e = 0; e < sTCnt; ++e) {
                int rr = sTR[e] - n0;
                if (rr >= 0 && rr < 8) {
                    float add = sTV[e] * sH1c[sTC[e]][ln];
                    #pragma unroll
                    for (int r = 0; r < 8; ++r)
                        if (r == rr) agg[r] += add;
                }
            }
        }

        // ---- GEMM: 8 slices of 8 k; W2 from LDS, A via readlane ----
        #pragma unroll 1
        for (int s = 0; s < 8; ++s) {
            const int buf = s & 1;
            float4 p0, p1;
            if (s < 7) {   // issue next-slice loads (uniform branch)
                const float* p = w2base + (size_t)(s + 1) * 8 * H2DIM;
                p0 = *(const float4*)(p + 4 * t);
                p1 = *(const float4*)(p + 2048 + 4 * t);
            }
            #pragma unroll
            for (int k = 0; k < 8; ++k) {
                const float4 w0 = *(const float4*)&sW2[buf][k * H2DIM + 4 * ln];
                const float4 w1 = *(const float4*)&sW2[buf][k * H2DIM + 256 + 4 * ln];
                const int kk = s * 8 + k;   // wave-uniform lane index
                #pragma unroll
                for (int r = 0; r < 8; ++r) {
                    const float ar = __int_as_float(
                        __builtin_amdgcn_readlane(__float_as_int(agg[r]), kk));
                    a2[r][0] = fmaf(ar, w0.x, a2[r][0]);
                    a2[r][1] = fmaf(ar, w0.y, a2[r][1]);
                    a2[r][2] = fmaf(ar, w0.z, a2[r][2]);
                    a2[r][3] = fmaf(ar, w0.w, a2[r][3]);
                    a2[r][4] = fmaf(ar, w1.x, a2[r][4]);
                    a2[r][5] = fmaf(ar, w1.y, a2[r][5]);
                    a2[r][6] = fmaf(ar, w1.z, a2[r][6]);
                    a2[r][7] = fmaf(ar, w1.w, a2[r][7]);
                }
            }
            if (s < 7) {   // write next slice into the other buffer
                float* dst = &sW2[buf ^ 1][0];
                *(float4*)&dst[4 * t]        = p0;
                *(float4*)&dst[2048 + 4 * t] = p1;
            }
            __syncthreads();
        }
    }

    // ---- epilogue: relu + row-sum -> block partial -> global ----
    {
        const float4 bb0 = *(const float4*)&b2[4 * ln];
        const float4 bb1 = *(const float4*)&b2[256 + 4 * ln];
        const float bv[8] = {bb0.x, bb0.y, bb0.z, bb0.w, bb1.x, bb1.y, bb1.z, bb1.w};
        float sv[8];
        #pragma unroll
        for (int cc = 0; cc < 8; ++cc) sv[cc] = 0.f;
        #pragma unroll
        for (int r = 0; r < 8; ++r)
            #pragma unroll
            for (int cc = 0; cc < 8; ++cc)
                sv[cc] += fmaxf(a2[r][cc] + bv[cc], 0.f);
        #pragma unroll
        for (int q = 0; q < 4; ++q) {
            atomicAdd(&sPart[4 * ln + q],       sv[q]);
            atomicAdd(&sPart[256 + 4 * ln + q], sv[4 + q]);
        }
    }
    __syncthreads();
    atomicAdd(&acc[t], sPart[t]);
}

// ---------------------------------------------------------------------------
// head: out[c] = (acc/262144) . Wfc[:,c] + bfc[c]
// ---------------------------------------------------------------------------
__global__ void head_kernel(const float* __restrict__ acc,
                            const float* __restrict__ Wfc,
                            const float* __restrict__ bfc,
                            float* __restrict__ out)
{
    const int c = blockIdx.x * 256 + threadIdx.x;
    if (c >= H2DIM) return;
    const float scale = 1.0f / (64.0f * 4096.0f);
    float v = bfc[c];
    for (int j = 0; j < H2DIM; ++j)
        v = fmaf(acc[j] * scale, Wfc[j * H2DIM + c], v);
    out[c] = v;
}

extern "C" void kernel_launch(void* const* d_in, const int* in_sizes, int n_in,
                              void* d_out, int out_size, void* d_ws, size_t ws_size,
                              hipStream_t stream)
{
    const float* x   = (const float*)d_in[0];
    const int*   ei  = (const int*)  d_in[1];
    const float* W1  = (const float*)d_in[2];
    const float* b1  = (const float*)d_in[3];
    const float* W2  = (const float*)d_in[4];
    const float* b2  = (const float*)d_in[5];
    const float* Wfc = (const float*)d_in[6];
    const float* bfc = (const float*)d_in[7];
    float* out = (float*)d_out;

    float*  acc     = (float*)d_ws;                  // 512 f32
    float2* ell     = (float2*)(acc + H2DIM);        // 1024 float2
    int*    tailCnt = (int*)(ell + NODES * ELLW);    // 1
    int*    tailRow = tailCnt + 1;                   // 64
    int*    tailCol = tailRow + TAILMAX;             // 64
    float*  tailVal = (float*)(tailCol + TAILMAX);   // 64

    prep_kernel <<<1,      256, 0, stream>>>(ei, acc, ell, tailCnt,
                                             tailRow, tailCol, tailVal);
    frame_kernel<<<FRAMES, 512, 0, stream>>>(x, ell, tailCnt,
                                             tailRow, tailCol, tailVal,
                                             W1, b1, W2, b2, acc);
    head_kernel <<<2,      256, 0, stream>>>(acc, Wfc, bfc, out);
}

// Round 6
// 624.866 us; speedup vs baseline: 2.2271x; 2.2271x over previous
//
#include <hip/hip_runtime.h>

#define NODES   64
#define FRAMES  4096
#define INCH    9
#define H1DIM   256
#define H2DIM   512
#define NEDGE   256

#define CHUNK   64
#define ELLW    16
#define TAILMAX 64
#define AH1S    72    // f16 row stride of sAH1 (144 B, 16B-aligned, non-pow2)

typedef _Float16 half8_t __attribute__((ext_vector_type(8)));
typedef float    f32x16 __attribute__((ext_vector_type(16)));

// ---------------------------------------------------------------------------
// prep: dense normalized A (row=dst, self-loops) -> ELL[64][16] (val,col) +
// overflow tail. Zero global accumulator. int32/int64 edge_index handled.
// ---------------------------------------------------------------------------
__global__ void prep_kernel(const int* __restrict__ ei,
                            float* __restrict__ acc,
                            float2* __restrict__ ellG,
                            int* __restrict__ tailCntG,
                            int* __restrict__ tailRowG,
                            int* __restrict__ tailColG,
                            float* __restrict__ tailValG)
{
    __shared__ float sA[NODES * NODES];
    __shared__ float dis[NODES];
    __shared__ int   deg[NODES];
    __shared__ int   sTail;
    __shared__ int   flag;
    const int t = threadIdx.x;  // 256 threads
    if (t == 0) { flag = 0; sTail = 0; }
    for (int i = t; i < NODES * NODES; i += 256) sA[i] = 0.f;
    if (t < NODES) deg[t] = 1;  // self-loop
    __syncthreads();
    if (ei[2 * t + 1] != 0) atomicOr(&flag, 1);   // int64 detection
    __syncthreads();
    const bool is64 = (flag == 0);
    int s = 0, d = 0;
    if (t < NEDGE) {
        if (is64) { s = ei[2 * t];   d = ei[512 + 2 * t]; }
        else      { s = ei[t];       d = ei[NEDGE + t];   }
        atomicAdd(&deg[d], 1);
    }
    __syncthreads();
    if (t < NODES) dis[t] = rsqrtf((float)deg[t]);
    __syncthreads();
    if (t < NEDGE) atomicAdd(&sA[d * NODES + s], dis[s] * dis[d]);  // row = dst
    __syncthreads();
    if (t < NODES) sA[t * NODES + t] += dis[t] * dis[t];
    __syncthreads();
    if (t < NODES) {
        int j = 0;
        for (int m = 0; m < NODES; ++m) {
            float v = sA[t * NODES + m];
            if (v != 0.f) {
                if (j < ELLW) {
                    ellG[t * ELLW + j] = make_float2(v, __int_as_float(m));
                } else {
                    int idx = atomicAdd(&sTail, 1);
                    if (idx < TAILMAX) {
                        tailRowG[idx] = t; tailColG[idx] = m; tailValG[idx] = v;
                    }
                }
                ++j;
            }
        }
        for (; j < ELLW; ++j)
            ellG[t * ELLW + j] = make_float2(0.f, __int_as_float(0));
    }
    __syncthreads();
    if (t == 0) *tailCntG = (sTail < TAILMAX) ? sTail : TAILMAX;
    for (int i = t; i < H2DIM; i += 256) acc[i] = 0.f;
}

// ---------------------------------------------------------------------------
// w2frag: pre-swizzle W2 (256x512 fp32) into 32x32x16-f16 B-fragment order,
// split hi/lo. frag(kt,nt): lane l holds W2[16kt+8*(l>>5)+jj][32nt+(l&31)].
// One-time kernel: grid 256 (=16kt x 16nt), 64 threads.
// ---------------------------------------------------------------------------
__global__ void w2frag_kernel(const float* __restrict__ W2,
                              _Float16* __restrict__ fh,
                              _Float16* __restrict__ fl)
{
    const int frag = blockIdx.x;
    const int kt = frag >> 4, nt = frag & 15;
    const int l = threadIdx.x;
    const int j = nt * 32 + (l & 31);
    const int kbase = kt * 16 + (l >> 5) * 8;
    const size_t off = ((size_t)frag * 64 + l) * 8;
    #pragma unroll
    for (int jj = 0; jj < 8; ++jj) {
        float v = W2[(size_t)(kbase + jj) * H2DIM + j];
        _Float16 hv = (_Float16)v;
        fh[off + jj] = hv;
        fl[off + jj] = (_Float16)(v - (float)hv);
    }
}

// ---------------------------------------------------------------------------
// One block per frame. Per 64-K-chunk: layer1 fp32 -> ELL agg fp32 ->
// convert to f16 hi/lo (XOR-swizzled LDS) -> 4x mfma_f32_32x32x16_f16 k-steps
// with 3-term f16 split, accumulating in f32x16 a2[2][2] (64 AGPRs).
// Epilogue: relu+bias, col-sum (D-row mapping irrelevant), LDS+global atomics.
// LDS ~52.5 KB; target 2 blocks/CU via launch_bounds(512,4) (=128 reg cap).
// ---------------------------------------------------------------------------
__global__ __launch_bounds__(512, 4)
void frame_kernel(const float* __restrict__ x,
                  const float2* __restrict__ ellG,
                  const int* __restrict__ tailCntG,
                  const int* __restrict__ tailRowG,
                  const int* __restrict__ tailColG,
                  const float* __restrict__ tailValG,
                  const float* __restrict__ W1,
                  const float* __restrict__ b1,
                  const _Float16* __restrict__ w2fh,
                  const _Float16* __restrict__ w2fl,
                  const float* __restrict__ b2,
                  float* __restrict__ acc)
{
    __shared__ __align__(16) float2 sEll[NODES][ELLW];       //  8192 B
    __shared__ float sX [NODES][12];                         //  3072 B
    __shared__ float sAX[NODES][12];                         //  3072 B
    __shared__ __align__(16) float sH1c[NODES][66];          // 16896 B
    __shared__ __align__(16) _Float16 sAH1h[NODES * AH1S];   //  9216 B
    __shared__ __align__(16) _Float16 sAH1l[NODES * AH1S];   //  9216 B
    __shared__ float sPart[H2DIM];                           //  2048 B
    __shared__ int   sTR[TAILMAX];
    __shared__ int   sTC[TAILMAX];
    __shared__ float sTV[TAILMAX];
    __shared__ int   sTCnt;                                  // ~52.5 KB total

    const int t  = threadIdx.x;
    const int f  = blockIdx.x;
    const int wv = t >> 6;         // wave 0..7
    const int ln = t & 63;
    const int n0 = wv * 8;         // layer1/agg rows

    // ---- stage ELL, tail, X ----
    for (int i = t; i < NODES * ELLW; i += 512)
        sEll[i >> 4][i & (ELLW - 1)] = ellG[i];
    if (t == 0) sTCnt = *tailCntG;
    if (t < TAILMAX) { sTR[t] = tailRowG[t]; sTC[t] = tailColG[t]; sTV[t] = tailValG[t]; }
    sPart[t] = 0.f;
    for (int i = t; i < NODES * INCH; i += 512) {
        int n = i / INCH, c = i - n * INCH;
        sX[n][c] = x[(n * FRAMES + f) * INCH + c];
    }
    __syncthreads();

    // ---- AX = A*X via ELL (+tail) ----
    for (int i = t; i < NODES * INCH; i += 512) {
        int n = i / INCH, c = i - n * INCH;
        float v = 0.f;
        #pragma unroll
        for (int j = 0; j < ELLW; ++j) {
            float2 e = sEll[n][j];
            v = fmaf(e.x, sX[__float_as_int(e.y)][c], v);
        }
        sAX[n][c] = v;
    }
    if (sTCnt > 0) {
        __syncthreads();
        if (t < sTCnt * INCH) {
            int e = t / INCH, c = t - e * INCH;
            atomicAdd(&sAX[sTR[e]][c], sTV[e] * sX[sTC[e]][c]);
        }
    }
    __syncthreads();

    // ---- accumulators: [mt][nti], 32x32 tiles -> 64 fp32 regs (AGPR) ----
    f32x16 a2[2][2];
    #pragma unroll
    for (int m = 0; m < 2; ++m)
        #pragma unroll
        for (int i = 0; i < 2; ++i)
            #pragma unroll
            for (int q = 0; q < 16; ++q) a2[m][i][q] = 0.f;

    #pragma unroll 1
    for (int ch = 0; ch < 4; ++ch) {
        const int jb = ch * CHUNK;

        // ---- layer1 chunk (fp32): H1c[n][ln] = relu(AX@W1 + b1) ----
        {
            float h[8];
            const float bb = b1[jb + ln];
            #pragma unroll
            for (int r = 0; r < 8; ++r) h[r] = bb;
            #pragma unroll
            for (int c = 0; c < INCH; ++c) {
                const float w = W1[c * H1DIM + jb + ln];
                #pragma unroll
                for (int r = 0; r < 8; ++r)
                    h[r] = fmaf(sAX[n0 + r][c], w, h[r]);
            }
            #pragma unroll
            for (int r = 0; r < 8; ++r)
                sH1c[n0 + r][ln] = fmaxf(h[r], 0.f);
        }
        __syncthreads();   // B1

        // ---- agg (fp32 ELL) -> f16 hi/lo, XOR-swizzled rows ----
        #pragma unroll
        for (int r = 0; r < 8; ++r) {
            const int n = n0 + r;
            float v = 0.f;
            #pragma unroll
            for (int jx = 0; jx < ELLW; ++jx) {
                float2 e = sEll[n][jx];                           // b64 broadcast
                v = fmaf(e.x, sH1c[__float_as_int(e.y)][ln], v);  // lane-stride-1
            }
            if (sTCnt > 0) {
                #pragma unroll 1
                for (int e = 0; e < sTCnt; ++e)
                    if (sTR[e] == n) v += sTV[e] * sH1c[sTC[e]][ln];
            }
            const _Float16 hv = (_Float16)v;
            const _Float16 lv = (_Float16)(v - (float)hv);
            const int idx = n * AH1S + (ln ^ ((n & 7) << 3));
            sAH1h[idx] = hv;
            sAH1l[idx] = lv;
        }
        __syncthreads();   // B2

        // ---- MFMA: 4 k-steps of 32x32x16, 3-term f16 split ----
        #pragma unroll 1
        for (int s = 0; s < 4; ++s) {
            const int kt = ch * 4 + s;
            half8_t bh[2], bl[2];
            #pragma unroll
            for (int i = 0; i < 2; ++i) {
                const size_t off = ((size_t)(kt * 16 + (wv * 2 + i)) * 64 + ln) * 8;
                bh[i] = *(const half8_t*)(w2fh + off);   // coalesced dwordx4
                bl[i] = *(const half8_t*)(w2fl + off);
            }
            half8_t ah[2], al[2];
            #pragma unroll
            for (int m = 0; m < 2; ++m) {
                const int row = m * 32 + (ln & 31);
                const int o = row * AH1S +
                              ((s * 16 + (ln >> 5) * 8) ^ ((row & 7) << 3));
                ah[m] = *(const half8_t*)&sAH1h[o];      // b128, swizzled
                al[m] = *(const half8_t*)&sAH1l[o];
            }
            #pragma unroll
            for (int m = 0; m < 2; ++m)
                #pragma unroll
                for (int i = 0; i < 2; ++i) {
                    a2[m][i] = __builtin_amdgcn_mfma_f32_32x32x16_f16(ah[m], bh[i], a2[m][i], 0, 0, 0);
                    a2[m][i] = __builtin_amdgcn_mfma_f32_32x32x16_f16(ah[m], bl[i], a2[m][i], 0, 0, 0);
                    a2[m][i] = __builtin_amdgcn_mfma_f32_32x32x16_f16(al[m], bh[i], a2[m][i], 0, 0, 0);
                }
        }
        // no barrier needed here: next chunk's B1 orders sAH1 reuse
    }

    // ---- epilogue: relu + bias, column sums (row mapping irrelevant) ----
    {
        const int c32 = ln & 31;
        #pragma unroll
        for (int i = 0; i < 2; ++i) {
            const int j = (wv * 2 + i) * 32 + c32;
            const float bb = b2[j];
            float ssum = 0.f;
            #pragma unroll
            for (int m = 0; m < 2; ++m)
                #pragma unroll
                for (int q = 0; q < 16; ++q)
                    ssum += fmaxf(a2[m][i][q] + bb, 0.f);
            atomicAdd(&sPart[j], ssum);
        }
    }
    __syncthreads();
    atomicAdd(&acc[t], sPart[t]);
}

// ---------------------------------------------------------------------------
// head: out[c] = (acc/262144) . Wfc[:,c] + bfc[c]
// ---------------------------------------------------------------------------
__global__ void head_kernel(const float* __restrict__ acc,
                            const float* __restrict__ Wfc,
                            const float* __restrict__ bfc,
                            float* __restrict__ out)
{
    const int c = blockIdx.x * 256 + threadIdx.x;
    if (c >= H2DIM) return;
    const float scale = 1.0f / (64.0f * 4096.0f);
    float v = bfc[c];
    for (int j = 0; j < H2DIM; ++j)
        v = fmaf(acc[j] * scale, Wfc[j * H2DIM + c], v);
    out[c] = v;
}

extern "C" void kernel_launch(void* const* d_in, const int* in_sizes, int n_in,
                              void* d_out, int out_size, void* d_ws, size_t ws_size,
                              hipStream_t stream)
{
    const float* x   = (const float*)d_in[0];
    const int*   ei  = (const int*)  d_in[1];
    const float* W1  = (const float*)d_in[2];
    const float* b1  = (const float*)d_in[3];
    const float* W2  = (const float*)d_in[4];
    const float* b2  = (const float*)d_in[5];
    const float* Wfc = (const float*)d_in[6];
    const float* bfc = (const float*)d_in[7];
    float* out = (float*)d_out;

    // ws: w2 frags first (16B-aligned), then small fp32/int blocks
    _Float16* w2fh = (_Float16*)d_ws;                     // 131072 f16 = 256 KB
    _Float16* w2fl = w2fh + 16 * 16 * 64 * 8;             // 256 KB
    float*    acc  = (float*)(w2fl + 16 * 16 * 64 * 8);   // 512 f32
    float2*   ell  = (float2*)(acc + H2DIM);              // 1024 float2
    int*   tailCnt = (int*)(ell + NODES * ELLW);
    int*   tailRow = tailCnt + 1;
    int*   tailCol = tailRow + TAILMAX;
    float* tailVal = (float*)(tailCol + TAILMAX);

    prep_kernel  <<<1,      256, 0, stream>>>(ei, acc, ell, tailCnt,
                                              tailRow, tailCol, tailVal);
    w2frag_kernel<<<256,     64, 0, stream>>>(W2, w2fh, w2fl);
    frame_kernel <<<FRAMES, 512, 0, stream>>>(x, ell, tailCnt,
                                              tailRow, tailCol, tailVal,
                                              W1, b1, w2fh, w2fl, b2, acc);
    head_kernel  <<<2,      256, 0, stream>>>(acc, Wfc, bfc, out);
}

// Round 7
// 450.892 us; speedup vs baseline: 3.0864x; 1.3858x over previous
//
#include <hip/hip_runtime.h>

#define NODES   64
#define FRAMES  4096
#define INCH    9
#define H1DIM   256
#define H2DIM   512
#define NEDGE   256
#define CHUNK   64
#define ELLW    16
#define TAILMAX 64

typedef _Float16 half8_t __attribute__((ext_vector_type(8)));
typedef float    f32x16  __attribute__((ext_vector_type(16)));

// ---------------------------------------------------------------------------
// prep: dense normalized A (row=dst, self-loops) -> ELL[64][16] (val,col) +
// overflow tail. Zero global accumulator. int32/int64 edge_index handled.
// ---------------------------------------------------------------------------
__global__ void prep_kernel(const int* __restrict__ ei,
                            float* __restrict__ acc,
                            float2* __restrict__ ellG,
                            int* __restrict__ tailCntG,
                            int* __restrict__ tailRowG,
                            int* __restrict__ tailColG,
                            float* __restrict__ tailValG)
{
    __shared__ float sA[NODES * NODES];
    __shared__ float dis[NODES];
    __shared__ int   deg[NODES];
    __shared__ int   sTail;
    __shared__ int   flag;
    const int t = threadIdx.x;  // 256 threads
    if (t == 0) { flag = 0; sTail = 0; }
    for (int i = t; i < NODES * NODES; i += 256) sA[i] = 0.f;
    if (t < NODES) deg[t] = 1;  // self-loop
    __syncthreads();
    if (ei[2 * t + 1] != 0) atomicOr(&flag, 1);   // int64 detection
    __syncthreads();
    const bool is64 = (flag == 0);
    int s = 0, d = 0;
    if (t < NEDGE) {
        if (is64) { s = ei[2 * t];   d = ei[512 + 2 * t]; }
        else      { s = ei[t];       d = ei[NEDGE + t];   }
        atomicAdd(&deg[d], 1);
    }
    __syncthreads();
    if (t < NODES) dis[t] = rsqrtf((float)deg[t]);
    __syncthreads();
    if (t < NEDGE) atomicAdd(&sA[d * NODES + s], dis[s] * dis[d]);  // row = dst
    __syncthreads();
    if (t < NODES) sA[t * NODES + t] += dis[t] * dis[t];
    __syncthreads();
    if (t < NODES) {
        int j = 0;
        for (int m = 0; m < NODES; ++m) {
            float v = sA[t * NODES + m];
            if (v != 0.f) {
                if (j < ELLW) {
                    ellG[t * ELLW + j] = make_float2(v, __int_as_float(m));
                } else {
                    int idx = atomicAdd(&sTail, 1);
                    if (idx < TAILMAX) {
                        tailRowG[idx] = t; tailColG[idx] = m; tailValG[idx] = v;
                    }
                }
                ++j;
            }
        }
        for (; j < ELLW; ++j)
            ellG[t * ELLW + j] = make_float2(0.f, __int_as_float(0));
    }
    __syncthreads();
    if (t == 0) *tailCntG = (sTail < TAILMAX) ? sTail : TAILMAX;
    for (int i = t; i < H2DIM; i += 256) acc[i] = 0.f;
}

// ---------------------------------------------------------------------------
// w2frag: pre-swizzle W2 (256x512 fp32) into fused hi/lo B-fragment layout:
// w2f[frag][lane][0..7]=hi, [8..15]=lo, frag = kt*16+nt; lane l holds
// W2[kt*16+(l>>5)*8+jj][nt*32+(l&31)].  (same mapping round 6 validated)
// ---------------------------------------------------------------------------
__global__ void w2frag_kernel(const float* __restrict__ W2,
                              _Float16* __restrict__ w2f)
{
    const int frag = blockIdx.x;            // 256 frags
    const int kt = frag >> 4, nt = frag & 15;
    const int l = threadIdx.x;              // 64 threads
    const int j = nt * 32 + (l & 31);
    const int kbase = kt * 16 + (l >> 5) * 8;
    const size_t off = (size_t)frag * 1024 + (size_t)l * 16;
    #pragma unroll
    for (int jj = 0; jj < 8; ++jj) {
        float v = W2[(size_t)(kbase + jj) * H2DIM + j];
        _Float16 hv = (_Float16)v;
        w2f[off + jj]     = hv;
        w2f[off + 8 + jj] = (_Float16)(v - (float)hv);
    }
}

// ---------------------------------------------------------------------------
// One block (1024 thr, 16 waves) per frame. Per 64-K-chunk:
//   layer1 fp32 (4 rows/wave) -> ELL agg fp32 -> f16 hi/lo into fragment-
//   ordered LDS planes [g][n^g][8] (write 2 lanes/bank free; read = m97
//   linear b128 pattern) -> 4 k-steps x 6 mfma_f32_32x32x16_f16 (3-term
//   split) into a2[2] (32 AGPR/lane -> no spill under the 128-reg cap).
// Wave roles: layer1/agg rows 4wv..4wv+3; MFMA tile m=wv>>3, cols nt0=(wv&7)*2.
// LDS ~59.7 KB, 16 waves/CU.
// ---------------------------------------------------------------------------
__global__ __launch_bounds__(1024, 4)
void frame_kernel(const float* __restrict__ x,
                  const float2* __restrict__ ellG,
                  const int* __restrict__ tailCntG,
                  const int* __restrict__ tailRowG,
                  const int* __restrict__ tailColG,
                  const float* __restrict__ tailValG,
                  const float* __restrict__ W1,
                  const float* __restrict__ b1,
                  const _Float16* __restrict__ w2f,
                  const float* __restrict__ b2,
                  float* __restrict__ acc)
{
    __shared__ __align__(16) float2 sEll[NODES][ELLW];   //  8192 B
    __shared__ float sX [NODES][12];                     //  3072 B
    __shared__ float sAX[NODES][12];                     //  3072 B
    __shared__ __align__(16) float sW1[INCH][H1DIM];     //  9216 B
    __shared__ float sH1c[NODES][66];                    // 16896 B
    __shared__ __align__(16) _Float16 sAH1[8192];        // 16384 B: [2 planes][8 g][64][8]
    __shared__ float sPart[H2DIM];                       //  2048 B
    __shared__ int   sTR[TAILMAX];
    __shared__ int   sTC[TAILMAX];
    __shared__ float sTV[TAILMAX];
    __shared__ int   sTCnt;                              // => ~59.7 KB

    const int t  = threadIdx.x;
    const int f  = blockIdx.x;
    const int wv = t >> 6;           // 0..15
    const int ln = t & 63;
    const int n0 = wv * 4;           // layer1/agg rows
    const int m   = wv >> 3;         // MFMA row tile (0..1)
    const int nt0 = (wv & 7) * 2;    // MFMA col tiles nt0, nt0+1
    const int lh = ln >> 5, l31 = ln & 31;

    // ---- stage ELL, tail, W1, X ----
    for (int i = t; i < NODES * ELLW; i += 1024)
        sEll[i >> 4][i & 15] = ellG[i];
    if (t == 0) sTCnt = *tailCntG;
    if (t < TAILMAX) { sTR[t] = tailRowG[t]; sTC[t] = tailColG[t]; sTV[t] = tailValG[t]; }
    if (t < H2DIM) sPart[t] = 0.f;
    for (int i = t; i < INCH * H1DIM; i += 1024)
        sW1[i >> 8][i & 255] = W1[i];
    if (t < NODES * INCH) {
        int n = t / INCH, c = t - n * INCH;
        sX[n][c] = x[(n * FRAMES + f) * INCH + c];
    }
    __syncthreads();

    // ---- AX = A*X via ELL (+tail) ----
    if (t < NODES * INCH) {
        int n = t / INCH, c = t - n * INCH;
        float v = 0.f;
        #pragma unroll
        for (int jx = 0; jx < ELLW; ++jx) {
            float2 e = sEll[n][jx];
            v = fmaf(e.x, sX[__float_as_int(e.y)][c], v);
        }
        sAX[n][c] = v;
    }
    if (sTCnt > 0) {
        __syncthreads();
        if (t < sTCnt * INCH) {
            int e = t / INCH, c = t - e * INCH;
            atomicAdd(&sAX[sTR[e]][c], sTV[e] * sX[sTC[e]][c]);
        }
    }
    __syncthreads();

    f32x16 a2[2];
    #pragma unroll
    for (int q = 0; q < 16; ++q) { a2[0][q] = 0.f; a2[1][q] = 0.f; }

    const int gA = ln >> 3, jA = ln & 7;   // agg write mapping: k=ln

    #pragma unroll 1
    for (int ch = 0; ch < 4; ++ch) {
        const int jb = ch * CHUNK;

        // ---- layer1 (fp32): H1c[n][ln] = relu(AX@W1 + b1), 4 rows/wave ----
        {
            float h[4];
            const float bb = b1[jb + ln];
            #pragma unroll
            for (int r = 0; r < 4; ++r) h[r] = bb;
            #pragma unroll
            for (int c = 0; c < INCH; ++c) {
                const float w = sW1[c][jb + ln];
                #pragma unroll
                for (int r = 0; r < 4; ++r)
                    h[r] = fmaf(sAX[n0 + r][c], w, h[r]);
            }
            #pragma unroll
            for (int r = 0; r < 4; ++r)
                sH1c[n0 + r][ln] = fmaxf(h[r], 0.f);
        }
        __syncthreads();   // B1: sH1c ready; also fences prev-ch sAH1 reads

        // ---- agg (fp32 ELL) -> f16 hi/lo fragment-ordered planes ----
        #pragma unroll
        for (int r = 0; r < 4; ++r) {
            const int n = n0 + r;
            float v = 0.f;
            #pragma unroll
            for (int jx = 0; jx < ELLW; ++jx) {
                float2 e = sEll[n][jx];                           // b64 broadcast
                v = fmaf(e.x, sH1c[__float_as_int(e.y)][ln], v);  // lane-stride-1
            }
            if (sTCnt > 0) {   // virtually never taken
                #pragma unroll 1
                for (int e = 0; e < sTCnt; ++e)
                    if (sTR[e] == n) v += sTV[e] * sH1c[sTC[e]][ln];
            }
            const _Float16 hv = (_Float16)v;
            const int idx = gA * 512 + ((n ^ gA) << 3) + jA;
            sAH1[idx]        = hv;                       // hi plane
            sAH1[4096 + idx] = (_Float16)(v - (float)hv); // lo plane
        }
        __syncthreads();   // B2: sAH1 ready

        // ---- MFMA: 4 k-steps x 6 mfma (hh, lh, hl) ----
        #pragma unroll 2
        for (int s = 0; s < 4; ++s) {
            const _Float16* bp = w2f +
                ((size_t)((ch * 4 + s) * 16 + nt0) * 1024 + (size_t)ln * 16);
            const half8_t bh0 = *(const half8_t*)(bp);          // imm 0
            const half8_t bl0 = *(const half8_t*)(bp + 8);      // imm 16
            const half8_t bh1 = *(const half8_t*)(bp + 1024);   // imm 2048
            const half8_t bl1 = *(const half8_t*)(bp + 1032);   // imm 2064
            const int gg = 2 * s + lh;
            const int aoff = gg * 512 + (((32 * m + l31) ^ gg) << 3);
            const half8_t ah = *(const half8_t*)&sAH1[aoff];
            const half8_t al = *(const half8_t*)&sAH1[4096 + aoff];
            a2[0] = __builtin_amdgcn_mfma_f32_32x32x16_f16(ah, bh0, a2[0], 0, 0, 0);
            a2[1] = __builtin_amdgcn_mfma_f32_32x32x16_f16(ah, bh1, a2[1], 0, 0, 0);
            a2[0] = __builtin_amdgcn_mfma_f32_32x32x16_f16(al, bh0, a2[0], 0, 0, 0);
            a2[1] = __builtin_amdgcn_mfma_f32_32x32x16_f16(al, bh1, a2[1], 0, 0, 0);
            a2[0] = __builtin_amdgcn_mfma_f32_32x32x16_f16(ah, bl0, a2[0], 0, 0, 0);
            a2[1] = __builtin_amdgcn_mfma_f32_32x32x16_f16(ah, bl1, a2[1], 0, 0, 0);
        }
        // next ch's B1 barrier orders sAH1 reuse (ds_reads drain at barrier)
    }

    // ---- epilogue: relu + bias, column sums (row mapping irrelevant) ----
    #pragma unroll
    for (int i = 0; i < 2; ++i) {
        const int j = (nt0 + i) * 32 + l31;
        const float bb = b2[j];
        float ssum = 0.f;
        #pragma unroll
        for (int q = 0; q < 16; ++q)
            ssum += fmaxf(a2[i][q] + bb, 0.f);
        atomicAdd(&sPart[j], ssum);   // m=0 and m=1 waves both add here
    }
    __syncthreads();
    if (t < H2DIM) atomicAdd(&acc[t], sPart[t]);
}

// ---------------------------------------------------------------------------
// head: out[c] = (acc/262144) . Wfc[:,c] + bfc[c]
// ---------------------------------------------------------------------------
__global__ void head_kernel(const float* __restrict__ acc,
                            const float* __restrict__ Wfc,
                            const float* __restrict__ bfc,
                            float* __restrict__ out)
{
    const int c = blockIdx.x * 256 + threadIdx.x;
    if (c >= H2DIM) return;
    const float scale = 1.0f / (64.0f * 4096.0f);
    float v = bfc[c];
    for (int j = 0; j < H2DIM; ++j)
        v = fmaf(acc[j] * scale, Wfc[j * H2DIM + c], v);
    out[c] = v;
}

extern "C" void kernel_launch(void* const* d_in, const int* in_sizes, int n_in,
                              void* d_out, int out_size, void* d_ws, size_t ws_size,
                              hipStream_t stream)
{
    const float* x   = (const float*)d_in[0];
    const int*   ei  = (const int*)  d_in[1];
    const float* W1  = (const float*)d_in[2];
    const float* b1  = (const float*)d_in[3];
    const float* W2  = (const float*)d_in[4];
    const float* b2  = (const float*)d_in[5];
    const float* Wfc = (const float*)d_in[6];
    const float* bfc = (const float*)d_in[7];
    float* out = (float*)d_out;

    _Float16* w2f  = (_Float16*)d_ws;                 // 256 frags x 1024 f16 = 512 KB
    float*    acc  = (float*)(w2f + 256 * 1024);      // 512 f32
    float2*   ell  = (float2*)(acc + H2DIM);          // 1024 float2
    int*   tailCnt = (int*)(ell + NODES * ELLW);
    int*   tailRow = tailCnt + 1;
    int*   tailCol = tailRow + TAILMAX;
    float* tailVal = (float*)(tailCol + TAILMAX);

    prep_kernel  <<<1,      256,  0, stream>>>(ei, acc, ell, tailCnt,
                                               tailRow, tailCol, tailVal);
    w2frag_kernel<<<256,     64,  0, stream>>>(W2, w2f);
    frame_kernel <<<FRAMES, 1024, 0, stream>>>(x, ell, tailCnt,
                                               tailRow, tailCol, tailVal,
                                               W1, b1, w2f, b2, acc);
    head_kernel  <<<2,      256,  0, stream>>>(acc, Wfc, bfc, out);
}

// Round 8
// 367.982 us; speedup vs baseline: 3.7818x; 1.2253x over previous
//
#include <hip/hip_runtime.h>

#define NODES   64
#define FRAMES  4096
#define INCH    9
#define H1DIM   256
#define H2DIM   512
#define NEDGE   256
#define CHUNK   64
#define ELLW    16
#define TAILMAX 64

typedef _Float16 half8_t __attribute__((ext_vector_type(8)));
typedef float    f32x16  __attribute__((ext_vector_type(16)));

// ---------------------------------------------------------------------------
// prep: dense normalized A (row=dst, self-loops) -> Adense (global, fp32),
// ELL[64][16] + tail (for the tiny A@X only), zero acc. int32/int64 handled.
// ---------------------------------------------------------------------------
__global__ void prep_kernel(const int* __restrict__ ei,
                            float* __restrict__ acc,
                            float2* __restrict__ ellG,
                            int* __restrict__ tailCntG,
                            int* __restrict__ tailRowG,
                            int* __restrict__ tailColG,
                            float* __restrict__ tailValG,
                            float* __restrict__ AdenseG)
{
    __shared__ float sA[NODES * NODES];
    __shared__ float dis[NODES];
    __shared__ int   deg[NODES];
    __shared__ int   sTail;
    __shared__ int   flag;
    const int t = threadIdx.x;  // 256 threads
    if (t == 0) { flag = 0; sTail = 0; }
    for (int i = t; i < NODES * NODES; i += 256) sA[i] = 0.f;
    if (t < NODES) deg[t] = 1;  // self-loop
    __syncthreads();
    if (ei[2 * t + 1] != 0) atomicOr(&flag, 1);   // int64 detection
    __syncthreads();
    const bool is64 = (flag == 0);
    int s = 0, d = 0;
    if (t < NEDGE) {
        if (is64) { s = ei[2 * t];   d = ei[512 + 2 * t]; }
        else      { s = ei[t];       d = ei[NEDGE + t];   }
        atomicAdd(&deg[d], 1);
    }
    __syncthreads();
    if (t < NODES) dis[t] = rsqrtf((float)deg[t]);
    __syncthreads();
    if (t < NEDGE) atomicAdd(&sA[d * NODES + s], dis[s] * dis[d]);  // row = dst
    __syncthreads();
    if (t < NODES) sA[t * NODES + t] += dis[t] * dis[t];
    __syncthreads();
    for (int i = t; i < NODES * NODES; i += 256) AdenseG[i] = sA[i];
    if (t < NODES) {
        int j = 0;
        for (int m = 0; m < NODES; ++m) {
            float v = sA[t * NODES + m];
            if (v != 0.f) {
                if (j < ELLW) {
                    ellG[t * ELLW + j] = make_float2(v, __int_as_float(m));
                } else {
                    int idx = atomicAdd(&sTail, 1);
                    if (idx < TAILMAX) {
                        tailRowG[idx] = t; tailColG[idx] = m; tailValG[idx] = v;
                    }
                }
                ++j;
            }
        }
        for (; j < ELLW; ++j)
            ellG[t * ELLW + j] = make_float2(0.f, __int_as_float(0));
    }
    __syncthreads();
    if (t == 0) *tailCntG = (sTail < TAILMAX) ? sTail : TAILMAX;
    for (int i = t; i < H2DIM; i += 256) acc[i] = 0.f;
}

// ---------------------------------------------------------------------------
// w2frag: W2 (256x512 fp32) -> fused hi/lo B-frags [frag=kt*16+nt][lane][16].
// (validated rounds 6/7)
// ---------------------------------------------------------------------------
__global__ void w2frag_kernel(const float* __restrict__ W2,
                              _Float16* __restrict__ w2f)
{
    const int frag = blockIdx.x;            // 256 frags
    const int kt = frag >> 4, nt = frag & 15;
    const int l = threadIdx.x;              // 64 threads
    const int j = nt * 32 + (l & 31);
    const int kbase = kt * 16 + (l >> 5) * 8;
    const size_t off = (size_t)frag * 1024 + (size_t)l * 16;
    #pragma unroll
    for (int jj = 0; jj < 8; ++jj) {
        float v = W2[(size_t)(kbase + jj) * H2DIM + j];
        _Float16 hv = (_Float16)v;
        w2f[off + jj]     = hv;
        w2f[off + 8 + jj] = (_Float16)(v - (float)hv);
    }
}

// ---------------------------------------------------------------------------
// w1afrag: blocks 0-7: W1 (9x256, K-padded to 16) -> B-frags [nt][lane][16];
//          blocks 8-15: Adense -> A-frags [mt*4+kt][lane][16] (hi|lo fused).
// A-operand layout: lane l holds A[32mt + (l&31)][16kt + (l>>5)*8 + jj].
// ---------------------------------------------------------------------------
__global__ void w1afrag_kernel(const float* __restrict__ W1,
                               const float* __restrict__ Adense,
                               _Float16* __restrict__ w1f,
                               _Float16* __restrict__ af)
{
    const int b = blockIdx.x;   // 16
    const int l = threadIdx.x;  // 64
    if (b < 8) {
        const size_t off = (size_t)(b * 64 + l) * 16;
        #pragma unroll
        for (int jj = 0; jj < 8; ++jj) {
            const int r = (l >> 5) * 8 + jj;
            float v = (r < INCH) ? W1[r * H1DIM + b * 32 + (l & 31)] : 0.f;
            _Float16 hv = (_Float16)v;
            w1f[off + jj]     = hv;
            w1f[off + 8 + jj] = (_Float16)(v - (float)hv);
        }
    } else {
        const int fa = b - 8;                 // mt*4 + kt
        const int mt = fa >> 2, kt = fa & 3;
        const size_t off = (size_t)(fa * 64 + l) * 16;
        #pragma unroll
        for (int jj = 0; jj < 8; ++jj) {
            float v = Adense[(32 * mt + (l & 31)) * NODES + 16 * kt + (l >> 5) * 8 + jj];
            _Float16 hv = (_Float16)v;
            af[off + jj]     = hv;
            af[off + 8 + jj] = (_Float16)(v - (float)hv);
        }
    }
}

// ---------------------------------------------------------------------------
// One block (1024 thr, 16 waves) per frame. All GEMMs on the matrix pipe:
//  prologue: X stage, AX = A@X via ELL (+tail), AX -> f16 hi/lo A-frags.
//  per chunk: P1 (waves 0-3):  H1c = relu(AXf @ W1f + b1)  [1 k-step x3 mfma]
//                              D-regs -> B-frag hi/lo LDS (b16 scatter)
//             P2 (waves 4-7):  AH1c = A @ H1c  [4 kt x3 mfma, dense A frags]
//                              D-regs -> A-frag hi/lo LDS
//             P3 (all 16):     a2 += AH1c @ W2[chunk]  [4 s x6 mfma]
//  2 barriers/chunk (P3 -> next P2 ordered by next chunk's bar1).
// D layout: col=lane&31, row=(reg&3)+8*(reg>>2)+4*(lane>>5)  [m74/m101].
// LDS ~54 KB -> 2 blocks/CU; regs ~100 < 128 cap (launch_bounds 1024,4).
// ---------------------------------------------------------------------------
__global__ __launch_bounds__(1024, 4)
void frame_kernel(const float* __restrict__ x,
                  const float2* __restrict__ ellG,
                  const int* __restrict__ tailCntG,
                  const int* __restrict__ tailRowG,
                  const int* __restrict__ tailColG,
                  const float* __restrict__ tailValG,
                  const float* __restrict__ b1,
                  const _Float16* __restrict__ w1f,
                  const _Float16* __restrict__ af,
                  const _Float16* __restrict__ w2f,
                  const float* __restrict__ b2,
                  float* __restrict__ acc)
{
    __shared__ __align__(16) float2 sEll[NODES][ELLW];   //  8192 B
    __shared__ float sX [NODES][12];                     //  3072 B
    __shared__ float sAX[NODES][12];                     //  3072 B
    __shared__ __align__(16) _Float16 sAXf[2048];        //  4096 B [pl][mt][l][8]
    __shared__ __align__(16) _Float16 sH1f[8192];        // 16384 B [pl][frag][l][8]
    __shared__ __align__(16) _Float16 sAH1f[8192];       // 16384 B [pl][frag][l][8]
    __shared__ float sPart[H2DIM];                       //  2048 B
    __shared__ int   sTR[TAILMAX];
    __shared__ int   sTC[TAILMAX];
    __shared__ float sTV[TAILMAX];
    __shared__ int   sTCnt;                              // => ~54 KB

    const int t   = threadIdx.x;
    const int f   = blockIdx.x;
    const int wv  = t >> 6;          // 0..15
    const int ln  = t & 63;
    const int lh  = ln >> 5, l31 = ln & 31;

    // ---- stage ELL, tail, X ----
    for (int i = t; i < NODES * ELLW; i += 1024)
        sEll[i >> 4][i & 15] = ellG[i];
    if (t == 0) sTCnt = *tailCntG;
    if (t < TAILMAX) { sTR[t] = tailRowG[t]; sTC[t] = tailColG[t]; sTV[t] = tailValG[t]; }
    if (t < H2DIM) sPart[t] = 0.f;
    if (t < NODES * INCH) {
        int n = t / INCH, c = t - n * INCH;
        sX[n][c] = x[(n * FRAMES + f) * INCH + c];
    }
    __syncthreads();

    // ---- AX = A@X via ELL (+tail), fp32 exact ----
    if (t < NODES * INCH) {
        int n = t / INCH, c = t - n * INCH;
        float v = 0.f;
        #pragma unroll
        for (int jx = 0; jx < ELLW; ++jx) {
            float2 e = sEll[n][jx];
            v = fmaf(e.x, sX[__float_as_int(e.y)][c], v);
        }
        sAX[n][c] = v;
    }
    if (sTCnt > 0) {
        __syncthreads();
        if (t < sTCnt * INCH) {
            int e = t / INCH, c = t - e * INCH;
            atomicAdd(&sAX[sTR[e]][c], sTV[e] * sX[sTC[e]][c]);
        }
    }
    __syncthreads();

    // ---- AX -> f16 hi/lo A-frags (K padded 9->16) ----
    {
        const int row = t >> 4, col = t & 15;
        const float v = (col < INCH) ? sAX[row][col] : 0.f;
        const _Float16 hv = (_Float16)v;
        const _Float16 lv = (_Float16)(v - (float)hv);
        const int idx = (row >> 5) * 512 +
                        (((col >> 3) << 5) | (row & 31)) * 8 + (col & 7);
        sAXf[idx]        = hv;
        sAXf[1024 + idx] = lv;
    }
    __syncthreads();

    f32x16 a2[2];
    #pragma unroll
    for (int q = 0; q < 16; ++q) { a2[0][q] = 0.f; a2[1][q] = 0.f; }

    #pragma unroll 1
    for (int ch = 0; ch < 4; ++ch) {
        // ---- P1: layer1 chunk on MFMA (waves 0-3) ----
        if (wv < 4) {
            const int mtL = wv >> 1, ntL = wv & 1;
            const half8_t axh = *(const half8_t*)&sAXf[mtL * 512 + ln * 8];
            const half8_t axl = *(const half8_t*)&sAXf[1024 + mtL * 512 + ln * 8];
            const _Float16* wp = w1f + (size_t)((ch * 2 + ntL) * 64 + ln) * 16;
            const half8_t wh = *(const half8_t*)wp;
            const half8_t wl = *(const half8_t*)(wp + 8);
            f32x16 d;
            #pragma unroll
            for (int q = 0; q < 16; ++q) d[q] = 0.f;
            d = __builtin_amdgcn_mfma_f32_32x32x16_f16(axh, wh, d, 0, 0, 0);
            d = __builtin_amdgcn_mfma_f32_32x32x16_f16(axl, wh, d, 0, 0, 0);
            d = __builtin_amdgcn_mfma_f32_32x32x16_f16(axh, wl, d, 0, 0, 0);
            const float bb = b1[ch * 64 + ntL * 32 + l31];
            #pragma unroll
            for (int q = 0; q < 16; ++q) {
                const int node = mtL * 32 + (q & 3) + ((q >> 2) << 3) + (lh << 2);
                const float v = fmaxf(d[q] + bb, 0.f);
                const _Float16 hv = (_Float16)v;
                const _Float16 lv = (_Float16)(v - (float)hv);
                const int idx = ((node >> 4) * 2 + ntL) * 512 +
                                ((((node >> 3) & 1) << 5) | l31) * 8 + (node & 7);
                sH1f[idx]        = hv;
                sH1f[4096 + idx] = lv;
            }
        }
        __syncthreads();   // B1: sH1f ready (also orders prev P3 vs this P2)

        // ---- P2: aggregation on MFMA, dense A (waves 4-7) ----
        if ((wv & 12) == 4) {
            const int ww = wv - 4;
            const int mtA = ww >> 1, ntc = ww & 1;
            f32x16 d;
            #pragma unroll
            for (int q = 0; q < 16; ++q) d[q] = 0.f;
            #pragma unroll 2
            for (int kt = 0; kt < 4; ++kt) {
                const _Float16* ap = af + (size_t)((mtA * 4 + kt) * 64 + ln) * 16;
                const half8_t ah = *(const half8_t*)ap;
                const half8_t al = *(const half8_t*)(ap + 8);
                const int fb = kt * 2 + ntc;
                const half8_t bh = *(const half8_t*)&sH1f[fb * 512 + ln * 8];
                const half8_t bl = *(const half8_t*)&sH1f[4096 + fb * 512 + ln * 8];
                d = __builtin_amdgcn_mfma_f32_32x32x16_f16(ah, bh, d, 0, 0, 0);
                d = __builtin_amdgcn_mfma_f32_32x32x16_f16(al, bh, d, 0, 0, 0);
                d = __builtin_amdgcn_mfma_f32_32x32x16_f16(ah, bl, d, 0, 0, 0);
            }
            #pragma unroll
            for (int q = 0; q < 16; ++q) {
                const int node = mtA * 32 + (q & 3) + ((q >> 2) << 3) + (lh << 2);
                const int kcol = ntc * 32 + l31;
                const float v = d[q];
                const _Float16 hv = (_Float16)v;
                const _Float16 lv = (_Float16)(v - (float)hv);
                const int idx = (mtA * 4 + (kcol >> 4)) * 512 +
                                ((node & 31) | (((kcol >> 3) & 1) << 5)) * 8 + (kcol & 7);
                sAH1f[idx]        = hv;
                sAH1f[4096 + idx] = lv;
            }
        }
        __syncthreads();   // B2: sAH1f ready

        // ---- P3: W2 GEMM (all 16 waves) ----
        {
            const int mtW = wv >> 3;
            const int nt0 = (wv & 7) * 2;
            #pragma unroll 2
            for (int s = 0; s < 4; ++s) {
                const int fa = mtW * 4 + s;
                const half8_t ah = *(const half8_t*)&sAH1f[fa * 512 + ln * 8];
                const half8_t al = *(const half8_t*)&sAH1f[4096 + fa * 512 + ln * 8];
                const _Float16* bp = w2f +
                    ((size_t)((ch * 4 + s) * 16 + nt0) * 1024 + (size_t)ln * 16);
                const half8_t bh0 = *(const half8_t*)bp;
                const half8_t bl0 = *(const half8_t*)(bp + 8);
                const half8_t bh1 = *(const half8_t*)(bp + 1024);
                const half8_t bl1 = *(const half8_t*)(bp + 1032);
                a2[0] = __builtin_amdgcn_mfma_f32_32x32x16_f16(ah, bh0, a2[0], 0, 0, 0);
                a2[1] = __builtin_amdgcn_mfma_f32_32x32x16_f16(ah, bh1, a2[1], 0, 0, 0);
                a2[0] = __builtin_amdgcn_mfma_f32_32x32x16_f16(al, bh0, a2[0], 0, 0, 0);
                a2[1] = __builtin_amdgcn_mfma_f32_32x32x16_f16(al, bh1, a2[1], 0, 0, 0);
                a2[0] = __builtin_amdgcn_mfma_f32_32x32x16_f16(ah, bl0, a2[0], 0, 0, 0);
                a2[1] = __builtin_amdgcn_mfma_f32_32x32x16_f16(ah, bl1, a2[1], 0, 0, 0);
            }
        }
        // no barrier: next chunk's B1 orders P3 reads vs next P2 writes
    }

    // ---- epilogue: relu + bias, column sums (D row mapping irrelevant) ----
    {
        const int mtW = wv >> 3;
        const int nt0 = (wv & 7) * 2;
        (void)mtW;
        #pragma unroll
        for (int i = 0; i < 2; ++i) {
            const int j = (nt0 + i) * 32 + l31;
            const float bb = b2[j];
            float ssum = 0.f;
            #pragma unroll
            for (int q = 0; q < 16; ++q)
                ssum += fmaxf(a2[i][q] + bb, 0.f);
            atomicAdd(&sPart[j], ssum);
        }
    }
    __syncthreads();
    if (t < H2DIM) atomicAdd(&acc[t], sPart[t]);
}

// ---------------------------------------------------------------------------
// head: out[c] = (acc/262144) . Wfc[:,c] + bfc[c]
// ---------------------------------------------------------------------------
__global__ void head_kernel(const float* __restrict__ acc,
                            const float* __restrict__ Wfc,
                            const float* __restrict__ bfc,
                            float* __restrict__ out)
{
    const int c = blockIdx.x * 256 + threadIdx.x;
    if (c >= H2DIM) return;
    const float scale = 1.0f / (64.0f * 4096.0f);
    float v = bfc[c];
    for (int j = 0; j < H2DIM; ++j)
        v = fmaf(acc[j] * scale, Wfc[j * H2DIM + c], v);
    out[c] = v;
}

extern "C" void kernel_launch(void* const* d_in, const int* in_sizes, int n_in,
                              void* d_out, int out_size, void* d_ws, size_t ws_size,
                              hipStream_t stream)
{
    const float* x   = (const float*)d_in[0];
    const int*   ei  = (const int*)  d_in[1];
    const float* W1  = (const float*)d_in[2];
    const float* b1  = (const float*)d_in[3];
    const float* W2  = (const float*)d_in[4];
    const float* b2  = (const float*)d_in[5];
    const float* Wfc = (const float*)d_in[6];
    const float* bfc = (const float*)d_in[7];
    float* out = (float*)d_out;

    _Float16* w2f    = (_Float16*)d_ws;              // 256K halves = 512 KB
    _Float16* w1f    = w2f + 256 * 1024;             // 8192 halves = 16 KB
    _Float16* afr    = w1f + 8192;                   // 8192 halves = 16 KB
    float*    Adense = (float*)(afr + 8192);         // 4096 f32 = 16 KB
    float*    acc    = Adense + NODES * NODES;       // 512 f32
    float2*   ell    = (float2*)(acc + H2DIM);       // 1024 float2
    int*   tailCnt   = (int*)(ell + NODES * ELLW);
    int*   tailRow   = tailCnt + 1;
    int*   tailCol   = tailRow + TAILMAX;
    float* tailVal   = (float*)(tailCol + TAILMAX);

    prep_kernel   <<<1,      256,  0, stream>>>(ei, acc, ell, tailCnt,
                                                tailRow, tailCol, tailVal, Adense);
    w2frag_kernel <<<256,     64,  0, stream>>>(W2, w2f);
    w1afrag_kernel<<<16,      64,  0, stream>>>(W1, Adense, w1f, afr);
    frame_kernel  <<<FRAMES, 1024, 0, stream>>>(x, ell, tailCnt,
                                                tailRow, tailCol, tailVal,
                                                b1, w1f, afr, w2f, b2, acc);
    head_kernel   <<<2,      256,  0, stream>>>(acc, Wfc, bfc, out);
}

// Round 9
// 305.973 us; speedup vs baseline: 4.5482x; 1.2027x over previous
//
#include <hip/hip_runtime.h>

#define NODES   64
#define FRAMES  4096
#define INCH    9
#define H1DIM   256
#define H2DIM   512
#define NEDGE   256
#define CHUNK   64
#define ELLW    16
#define TAILMAX 64

typedef _Float16 half8_t __attribute__((ext_vector_type(8)));
typedef _Float16 half4_t __attribute__((ext_vector_type(4)));
typedef float    f32x16  __attribute__((ext_vector_type(16)));

// ---------------------------------------------------------------------------
// prep: dense normalized A (row=dst, self-loops) -> Adense (global, fp32),
// ELL[64][16] + tail (for the tiny A@X only), zero acc. int32/int64 handled.
// ---------------------------------------------------------------------------
__global__ void prep_kernel(const int* __restrict__ ei,
                            float* __restrict__ acc,
                            float2* __restrict__ ellG,
                            int* __restrict__ tailCntG,
                            int* __restrict__ tailRowG,
                            int* __restrict__ tailColG,
                            float* __restrict__ tailValG,
                            float* __restrict__ AdenseG)
{
    __shared__ float sA[NODES * NODES];
    __shared__ float dis[NODES];
    __shared__ int   deg[NODES];
    __shared__ int   sTail;
    __shared__ int   flag;
    const int t = threadIdx.x;  // 256 threads
    if (t == 0) { flag = 0; sTail = 0; }
    for (int i = t; i < NODES * NODES; i += 256) sA[i] = 0.f;
    if (t < NODES) deg[t] = 1;  // self-loop
    __syncthreads();
    if (ei[2 * t + 1] != 0) atomicOr(&flag, 1);   // int64 detection
    __syncthreads();
    const bool is64 = (flag == 0);
    int s = 0, d = 0;
    if (t < NEDGE) {
        if (is64) { s = ei[2 * t];   d = ei[512 + 2 * t]; }
        else      { s = ei[t];       d = ei[NEDGE + t];   }
        atomicAdd(&deg[d], 1);
    }
    __syncthreads();
    if (t < NODES) dis[t] = rsqrtf((float)deg[t]);
    __syncthreads();
    if (t < NEDGE) atomicAdd(&sA[d * NODES + s], dis[s] * dis[d]);  // row = dst
    __syncthreads();
    if (t < NODES) sA[t * NODES + t] += dis[t] * dis[t];
    __syncthreads();
    for (int i = t; i < NODES * NODES; i += 256) AdenseG[i] = sA[i];
    if (t < NODES) {
        int j = 0;
        for (int m = 0; m < NODES; ++m) {
            float v = sA[t * NODES + m];
            if (v != 0.f) {
                if (j < ELLW) {
                    ellG[t * ELLW + j] = make_float2(v, __int_as_float(m));
                } else {
                    int idx = atomicAdd(&sTail, 1);
                    if (idx < TAILMAX) {
                        tailRowG[idx] = t; tailColG[idx] = m; tailValG[idx] = v;
                    }
                }
                ++j;
            }
        }
        for (; j < ELLW; ++j)
            ellG[t * ELLW + j] = make_float2(0.f, __int_as_float(0));
    }
    __syncthreads();
    if (t == 0) *tailCntG = (sTail < TAILMAX) ? sTail : TAILMAX;
    for (int i = t; i < H2DIM; i += 256) acc[i] = 0.f;
}

// ---------------------------------------------------------------------------
// w2frag: W2 (256x512 fp32) -> fused hi/lo B-frags [frag=kt*16+nt][lane][16].
// (validated rounds 6-8)
// ---------------------------------------------------------------------------
__global__ void w2frag_kernel(const float* __restrict__ W2,
                              _Float16* __restrict__ w2f)
{
    const int frag = blockIdx.x;            // 256 frags
    const int kt = frag >> 4, nt = frag & 15;
    const int l = threadIdx.x;              // 64 threads
    const int j = nt * 32 + (l & 31);
    const int kbase = kt * 16 + (l >> 5) * 8;
    const size_t off = (size_t)frag * 1024 + (size_t)l * 16;
    #pragma unroll
    for (int jj = 0; jj < 8; ++jj) {
        float v = W2[(size_t)(kbase + jj) * H2DIM + j];
        _Float16 hv = (_Float16)v;
        w2f[off + jj]     = hv;
        w2f[off + 8 + jj] = (_Float16)(v - (float)hv);
    }
}

// ---------------------------------------------------------------------------
// w1afrag: blocks 0-7: W1 (9x256, K-padded to 16) -> B-frags [nt][lane][16];
//          blocks 8-15: Adense -> AT B-frags: af[fa=nt2*4+kt2][lane][16]:
//          lane l holds AT[16kt2+8*(l>>5)+jj][32nt2+(l&31)]
//                      = A[32nt2+(l&31)][16kt2+8*(l>>5)+jj]. (hi|lo fused)
// ---------------------------------------------------------------------------
__global__ void w1afrag_kernel(const float* __restrict__ W1,
                               const float* __restrict__ Adense,
                               _Float16* __restrict__ w1f,
                               _Float16* __restrict__ af)
{
    const int b = blockIdx.x;   // 16
    const int l = threadIdx.x;  // 64
    if (b < 8) {
        const size_t off = (size_t)(b * 64 + l) * 16;
        #pragma unroll
        for (int jj = 0; jj < 8; ++jj) {
            const int r = (l >> 5) * 8 + jj;
            float v = (r < INCH) ? W1[r * H1DIM + b * 32 + (l & 31)] : 0.f;
            _Float16 hv = (_Float16)v;
            w1f[off + jj]     = hv;
            w1f[off + 8 + jj] = (_Float16)(v - (float)hv);
        }
    } else {
        const int fa = b - 8;                 // nt2*4 + kt2
        const int nt2 = fa >> 2, kt2 = fa & 3;
        const size_t off = (size_t)(fa * 64 + l) * 16;
        #pragma unroll
        for (int jj = 0; jj < 8; ++jj) {
            float v = Adense[(32 * nt2 + (l & 31)) * NODES + 16 * kt2 + (l >> 5) * 8 + jj];
            _Float16 hv = (_Float16)v;
            af[off + jj]     = hv;
            af[off + 8 + jj] = (_Float16)(v - (float)hv);
        }
    }
}

// ---------------------------------------------------------------------------
// One block (1024 thr, 16 waves) per frame.
//  P1 (waves 0-3): H1c = relu(AXf @ W1f + b1), D -> B-frag LDS, b64-packed.
//  P2 (waves 4-7): AH1cT = H1cT @ AT  (transposed MFMA: P1's B-frag output
//      IS the A-operand of H1cT; AT B-frags staged in LDS). D lands with
//      lane<->node -> A-frag store is 8 packed ds_write_b64 (no b16 scatter).
//  P3 (all 16):    wave = one n-tile (nt=wv), both m-tiles; a2[2] (32 AGPR);
//      w2f read once per block, register-prefetched one s-step ahead.
// 2 barriers/chunk. D layout: col=lane&31, row=(q&3)+8(q>>2)+4(lane>>5).
// LDS ~69 KB -> 2 blocks/CU; launch_bounds(1024,4) -> 128-reg cap, ~90 used.
// ---------------------------------------------------------------------------
__global__ __launch_bounds__(1024, 4)
void frame_kernel(const float* __restrict__ x,
                  const float2* __restrict__ ellG,
                  const int* __restrict__ tailCntG,
                  const int* __restrict__ tailRowG,
                  const int* __restrict__ tailColG,
                  const float* __restrict__ tailValG,
                  const float* __restrict__ b1,
                  const _Float16* __restrict__ w1f,
                  const _Float16* __restrict__ af,
                  const _Float16* __restrict__ w2f,
                  const float* __restrict__ b2,
                  float* __restrict__ acc)
{
    __shared__ __align__(16) float2 sEll[NODES][ELLW];   //  8192 B
    __shared__ float sX [NODES][12];                     //  3072 B
    __shared__ float sAX[NODES][12];                     //  3072 B
    __shared__ __align__(16) _Float16 sAXf[2048];        //  4096 B [pl][mt][fl][8]
    __shared__ __align__(16) _Float16 sH1f[8192];        // 16384 B [pl][frag][fl][8]
    __shared__ __align__(16) _Float16 sAH1f[8192];       // 16384 B [pl][frag][fl][8]
    __shared__ __align__(16) _Float16 sATfH[4096];       //  8192 B [fa][fl][8]
    __shared__ __align__(16) _Float16 sATfL[4096];       //  8192 B
    __shared__ float sPart[H2DIM];                       //  2048 B
    __shared__ int   sTR[TAILMAX];
    __shared__ int   sTC[TAILMAX];
    __shared__ float sTV[TAILMAX];
    __shared__ int   sTCnt;                              // => ~69 KB

    const int t   = threadIdx.x;
    const int f   = blockIdx.x;
    const int wv  = t >> 6;          // 0..15
    const int ln  = t & 63;
    const int lh  = ln >> 5, l31 = ln & 31;

    // ---- stage ELL, tail, ATf, X ----
    for (int i = t; i < NODES * ELLW; i += 1024)
        sEll[i >> 4][i & 15] = ellG[i];
    if (t == 0) sTCnt = *tailCntG;
    if (t < TAILMAX) { sTR[t] = tailRowG[t]; sTC[t] = tailColG[t]; sTV[t] = tailValG[t]; }
    if (t < H2DIM) sPart[t] = 0.f;
    if (t < 512) {   // split fused af -> separate hi/lo planes (conflict-free reads)
        const _Float16* ap = af + (size_t)t * 16;
        *(half8_t*)&sATfH[t * 8] = *(const half8_t*)ap;
        *(half8_t*)&sATfL[t * 8] = *(const half8_t*)(ap + 8);
    }
    if (t < NODES * INCH) {
        int n = t / INCH, c = t - n * INCH;
        sX[n][c] = x[(n * FRAMES + f) * INCH + c];
    }
    __syncthreads();

    // ---- AX = A@X via ELL (+tail), fp32 exact ----
    if (t < NODES * INCH) {
        int n = t / INCH, c = t - n * INCH;
        float v = 0.f;
        #pragma unroll
        for (int jx = 0; jx < ELLW; ++jx) {
            float2 e = sEll[n][jx];
            v = fmaf(e.x, sX[__float_as_int(e.y)][c], v);
        }
        sAX[n][c] = v;
    }
    if (sTCnt > 0) {
        __syncthreads();
        if (t < sTCnt * INCH) {
            int e = t / INCH, c = t - e * INCH;
            atomicAdd(&sAX[sTR[e]][c], sTV[e] * sX[sTC[e]][c]);
        }
    }
    __syncthreads();

    // ---- AX -> f16 hi/lo A-frags (K padded 9->16) ----
    {
        const int row = t >> 4, col = t & 15;
        const float v = (col < INCH) ? sAX[row][col] : 0.f;
        const _Float16 hv = (_Float16)v;
        const _Float16 lv = (_Float16)(v - (float)hv);
        const int idx = (row >> 5) * 512 +
                        (((col >> 3) << 5) | (row & 31)) * 8 + (col & 7);
        sAXf[idx]        = hv;
        sAXf[1024 + idx] = lv;
    }
    __syncthreads();

    f32x16 a2[2];
    #pragma unroll
    for (int q = 0; q < 16; ++q) { a2[0][q] = 0.f; a2[1][q] = 0.f; }

    #pragma unroll 1
    for (int ch = 0; ch < 4; ++ch) {
        // ---- P1: layer1 chunk on MFMA (waves 0-3) ----
        if (wv < 4) {
            const int mtL = wv >> 1, ntL = wv & 1;
            const half8_t axh = *(const half8_t*)&sAXf[mtL * 512 + ln * 8];
            const half8_t axl = *(const half8_t*)&sAXf[1024 + mtL * 512 + ln * 8];
            const _Float16* wp = w1f + (size_t)((ch * 2 + ntL) * 64 + ln) * 16;
            const half8_t wh = *(const half8_t*)wp;
            const half8_t wl = *(const half8_t*)(wp + 8);
            f32x16 d;
            #pragma unroll
            for (int q = 0; q < 16; ++q) d[q] = 0.f;
            d = __builtin_amdgcn_mfma_f32_32x32x16_f16(axh, wh, d, 0, 0, 0);
            d = __builtin_amdgcn_mfma_f32_32x32x16_f16(axl, wh, d, 0, 0, 0);
            d = __builtin_amdgcn_mfma_f32_32x32x16_f16(axh, wl, d, 0, 0, 0);
            const float bb = b1[ch * 64 + ntL * 32 + l31];
            #pragma unroll
            for (int j = 0; j < 4; ++j) {
                half4_t hv, lv;
                #pragma unroll
                for (int qq = 0; qq < 4; ++qq) {
                    const float v = fmaxf(d[4 * j + qq] + bb, 0.f);
                    const _Float16 h = (_Float16)v;
                    hv[qq] = h;
                    lv[qq] = (_Float16)(v - (float)h);
                }
                const int idx = ((2 * mtL + (j >> 1)) * 2 + ntL) * 512 +
                                (((j & 1) << 5) | l31) * 8 + 4 * lh;
                *(half4_t*)&sH1f[idx]        = hv;
                *(half4_t*)&sH1f[4096 + idx] = lv;
            }
        }
        __syncthreads();   // B1: sH1f ready

        // ---- P2: AH1cT = H1cT @ AT on MFMA (waves 4-7) ----
        if ((wv & 12) == 4) {
            const int ww = wv & 3;
            const int mt2 = ww >> 1;   // h1col tile (M of transposed gemm)
            const int nt2 = ww & 1;    // node_out tile (N)
            f32x16 d;
            #pragma unroll
            for (int q = 0; q < 16; ++q) d[q] = 0.f;
            #pragma unroll
            for (int kt2 = 0; kt2 < 4; ++kt2) {   // node_in 16-groups
                const int fb = kt2 * 2 + mt2;
                const half8_t ah = *(const half8_t*)&sH1f[fb * 512 + ln * 8];
                const half8_t al = *(const half8_t*)&sH1f[4096 + fb * 512 + ln * 8];
                const int fa = nt2 * 4 + kt2;
                const half8_t bh = *(const half8_t*)&sATfH[fa * 512 + ln * 8];
                const half8_t bl = *(const half8_t*)&sATfL[fa * 512 + ln * 8];
                d = __builtin_amdgcn_mfma_f32_32x32x16_f16(ah, bh, d, 0, 0, 0);
                d = __builtin_amdgcn_mfma_f32_32x32x16_f16(al, bh, d, 0, 0, 0);
                d = __builtin_amdgcn_mfma_f32_32x32x16_f16(ah, bl, d, 0, 0, 0);
            }
            // D: col(lane)=node_out, row(reg)=h1col -> A-frag store, b64-packed
            #pragma unroll
            for (int j = 0; j < 4; ++j) {
                half4_t hv, lv;
                #pragma unroll
                for (int qq = 0; qq < 4; ++qq) {
                    const float v = d[4 * j + qq];
                    const _Float16 h = (_Float16)v;
                    hv[qq] = h;
                    lv[qq] = (_Float16)(v - (float)h);
                }
                const int idx = (nt2 * 4 + 2 * mt2 + (j >> 1)) * 512 +
                                (((j & 1) << 5) | l31) * 8 + 4 * lh;
                *(half4_t*)&sAH1f[idx]        = hv;
                *(half4_t*)&sAH1f[4096 + idx] = lv;
            }
        }
        __syncthreads();   // B2: sAH1f ready

        // ---- P3: W2 GEMM, wave = n-tile nt=wv, both m-tiles ----
        {
            const _Float16* bp = w2f +
                ((size_t)(ch * 4) * 16 + wv) * 1024 + (size_t)ln * 16;
            half8_t bh = *(const half8_t*)bp;
            half8_t bl = *(const half8_t*)(bp + 8);
            #pragma unroll
            for (int s = 0; s < 4; ++s) {
                half8_t nbh, nbl;
                if (s < 3) {   // prefetch next k-group's B frags (16 KB stride)
                    nbh = *(const half8_t*)(bp + 16384);
                    nbl = *(const half8_t*)(bp + 16392);
                }
                const half8_t ah0 = *(const half8_t*)&sAH1f[s * 512 + ln * 8];
                const half8_t al0 = *(const half8_t*)&sAH1f[4096 + s * 512 + ln * 8];
                const half8_t ah1 = *(const half8_t*)&sAH1f[(4 + s) * 512 + ln * 8];
                const half8_t al1 = *(const half8_t*)&sAH1f[4096 + (4 + s) * 512 + ln * 8];
                a2[0] = __builtin_amdgcn_mfma_f32_32x32x16_f16(ah0, bh, a2[0], 0, 0, 0);
                a2[1] = __builtin_amdgcn_mfma_f32_32x32x16_f16(ah1, bh, a2[1], 0, 0, 0);
                a2[0] = __builtin_amdgcn_mfma_f32_32x32x16_f16(al0, bh, a2[0], 0, 0, 0);
                a2[1] = __builtin_amdgcn_mfma_f32_32x32x16_f16(al1, bh, a2[1], 0, 0, 0);
                a2[0] = __builtin_amdgcn_mfma_f32_32x32x16_f16(ah0, bl, a2[0], 0, 0, 0);
                a2[1] = __builtin_amdgcn_mfma_f32_32x32x16_f16(ah1, bl, a2[1], 0, 0, 0);
                if (s < 3) { bh = nbh; bl = nbl; bp += 16384; }
            }
        }
        // next chunk's B1 orders P3 reads vs next P2 writes
    }

    // ---- epilogue: relu + bias, column sums (D row mapping irrelevant) ----
    {
        const int j = wv * 32 + l31;
        const float bb = b2[j];
        float ssum = 0.f;
        #pragma unroll
        for (int q = 0; q < 16; ++q) {
            ssum += fmaxf(a2[0][q] + bb, 0.f);   // nodes tile 0
            ssum += fmaxf(a2[1][q] + bb, 0.f);   // nodes tile 1
        }
        atomicAdd(&sPart[j], ssum);              // 2-way (lh 0/1)
    }
    __syncthreads();
    if (t < H2DIM) atomicAdd(&acc[t], sPart[t]);
}

// ---------------------------------------------------------------------------
// head: out[c] = (acc/262144) . Wfc[:,c] + bfc[c]
// ---------------------------------------------------------------------------
__global__ void head_kernel(const float* __restrict__ acc,
                            const float* __restrict__ Wfc,
                            const float* __restrict__ bfc,
                            float* __restrict__ out)
{
    const int c = blockIdx.x * 256 + threadIdx.x;
    if (c >= H2DIM) return;
    const float scale = 1.0f / (64.0f * 4096.0f);
    float v = bfc[c];
    for (int j = 0; j < H2DIM; ++j)
        v = fmaf(acc[j] * scale, Wfc[j * H2DIM + c], v);
    out[c] = v;
}

extern "C" void kernel_launch(void* const* d_in, const int* in_sizes, int n_in,
                              void* d_out, int out_size, void* d_ws, size_t ws_size,
                              hipStream_t stream)
{
    const float* x   = (const float*)d_in[0];
    const int*   ei  = (const int*)  d_in[1];
    const float* W1  = (const float*)d_in[2];
    const float* b1  = (const float*)d_in[3];
    const float* W2  = (const float*)d_in[4];
    const float* b2  = (const float*)d_in[5];
    const float* Wfc = (const float*)d_in[6];
    const float* bfc = (const float*)d_in[7];
    float* out = (float*)d_out;

    _Float16* w2f    = (_Float16*)d_ws;              // 256K halves = 512 KB
    _Float16* w1f    = w2f + 256 * 1024;             // 8192 halves = 16 KB
    _Float16* afr    = w1f + 8192;                   // 8192 halves = 16 KB
    float*    Adense = (float*)(afr + 8192);         // 4096 f32 = 16 KB
    float*    acc    = Adense + NODES * NODES;       // 512 f32
    float2*   ell    = (float2*)(acc + H2DIM);       // 1024 float2
    int*   tailCnt   = (int*)(ell + NODES * ELLW);
    int*   tailRow   = tailCnt + 1;
    int*   tailCol   = tailRow + TAILMAX;
    float* tailVal   = (float*)(tailCol + TAILMAX);

    prep_kernel   <<<1,      256,  0, stream>>>(ei, acc, ell, tailCnt,
                                                tailRow, tailCol, tailVal, Adense);
    w2frag_kernel <<<256,     64,  0, stream>>>(W2, w2f);
    w1afrag_kernel<<<16,      64,  0, stream>>>(W1, Adense, w1f, afr);
    frame_kernel  <<<FRAMES, 1024, 0, stream>>>(x, ell, tailCnt,
                                                tailRow, tailCol, tailVal,
                                                b1, w1f, afr, w2f, b2, acc);
    head_kernel   <<<2,      256,  0, stream>>>(acc, Wfc, bfc, out);
}